// Round 12
// baseline (339.266 us; speedup 1.0000x reference)
//
#include <hip/hip_runtime.h>
#include <cmath>

#define SQ 4096
#define SK 4096
#define NH 16
#define DH 128
#define TQ 64
#define TK 64
#define TOPK 2048
#define NEG_SENTINEL (-3.0e38f)

typedef __attribute__((ext_vector_type(8))) short short8;
typedef __attribute__((ext_vector_type(4))) float f32x4;
typedef __attribute__((ext_vector_type(16))) float f32x16;

#define QS_BYTES ((size_t)64 * 16 * 2 * 1024 * 16)   // [qtile][head][part][unit16B]

// Split f32 x into bf16 hi + bf16 lo (truncation split; residual exact).
__device__ __forceinline__ void cvt8(const float4 x0, const float4 x1,
                                     short8& hv, short8& lv) {
    const float xs[8] = {x0.x, x0.y, x0.z, x0.w, x1.x, x1.y, x1.z, x1.w};
    #pragma unroll
    for (int j = 0; j < 8; ++j) {
        const unsigned int b = __float_as_uint(xs[j]);
        const float hf = __uint_as_float(b & 0xFFFF0000u);
        const float r = xs[j] - hf;
        hv[j] = (short)(b >> 16);
        lv[j] = (short)(__float_as_uint(r) >> 16);
    }
}

__device__ __forceinline__ void gload_lds16(const void* g, void* l) {
    __builtin_amdgcn_global_load_lds(
        (const __attribute__((address_space(1))) unsigned int*)g,
        (__attribute__((address_space(3))) unsigned int*)l,
        16, 0, 0);
}

// ---------------------------------------------------------------------------
// Kernel 0: pre-split Q (validated, unchanged).
// ---------------------------------------------------------------------------
__global__ __launch_bounds__(256) void split_q_kernel(
    const float* __restrict__ qg,    // [SQ][NH][DH]
    short8* __restrict__ qs)         // [64][16][2][1024] 16B units
{
    const int gidx = blockIdx.x * 256 + threadIdx.x;   // [row][h][c]
    const int c   = gidx & 15;
    const int h   = (gidx >> 4) & 15;
    const int row = gidx >> 8;
    const size_t gb = ((size_t)row * NH + h) * DH + c * 8;
    const float4 x0 = *(const float4*)&qg[gb];
    const float4 x1 = *(const float4*)&qg[gb + 4];
    short8 hv, lv;
    cvt8(x0, x1, hv, lv);
    const int tile = row >> 6;
    const int r    = row & 63;
    const int u    = c * 64 + (r ^ (c & 7));
    const size_t base = (size_t)(tile * 16 + h) * 2048;
    qs[base + u]        = hv;
    qs[base + 1024 + u] = lv;
}

// ---------------------------------------------------------------------------
// Kernel 1: scores — 32x32x16 MFMA with THREE independent accumulator chains
// (hh, hl, lh; summed before relu in the epilogue — identical math to r10's
// 16x16 version). Restores cross-MFMA ILP lost in round 11 while keeping the
// conflict-free 32x32 operand pattern and half the instruction count.
// ---------------------------------------------------------------------------
__global__ __launch_bounds__(256, 4) void scores_kernel(
    const short8* __restrict__ qs,   // pre-split Q
    const float* __restrict__ kg,    // [SK][DH]
    const float* __restrict__ wg,    // [SQ][NH]
    float* __restrict__ scores)      // [SQ][SK]
{
    const int bk = blockIdx.x;
    const int bq = blockIdx.y;
    const int qbase = bq * TQ;
    const int kbase = bk * TK;
    const int tid = threadIdx.x;

    if (bk > bq) {
        const float4 minf = make_float4(NEG_SENTINEL, NEG_SENTINEL, NEG_SENTINEL, NEG_SENTINEL);
        #pragma unroll
        for (int it = 0; it < 4; ++it) {
            int idx = it * 256 + tid;
            int r  = idx >> 4;
            int c4 = idx & 15;
            *(float4*)&scores[(size_t)(qbase + r) * SK + kbase + (c4 << 2)] = minf;
        }
        return;
    }

    __shared__ short8 QsH[1024], QsL[1024];   // 16KB + 16KB
    __shared__ float  Wl[TQ * NH];            // 4KB

    const int lane = tid & 63;
    const int wid  = tid >> 6;
    const int wr   = wid >> 1;     // q-half
    const int wc   = wid & 1;      // k-half
    const int l31  = lane & 31;
    const int hi5  = lane >> 5;    // 0/1

    #pragma unroll
    for (int it = 0; it < 4; ++it) {
        const int i = tid + it * 256;
        Wl[i] = wg[(size_t)qbase * NH + i] * 0.08838834764831845f;
    }

    // ---- K fragments in registers (once per block): col = l31, 8 k-steps ----
    short8 bh[8], bl[8];
    {
        const int kcol = kbase + wc * 32 + l31;
        #pragma unroll
        for (int s = 0; s < 8; ++s) {
            const int c = 2 * s + hi5;
            const float4 x0 = *(const float4*)&kg[(size_t)kcol * DH + c * 8];
            const float4 x1 = *(const float4*)&kg[(size_t)kcol * DH + c * 8 + 4];
            cvt8(x0, x1, bh[s], bl[s]);
        }
    }

    // A-fragment LDS unit offsets
    int uo[8];
    {
        const int row = wr * 32 + l31;
        #pragma unroll
        for (int s = 0; s < 8; ++s) {
            const int c = 2 * s + hi5;
            uo[s] = c * 64 + (row ^ (c & 7));
        }
    }

    f32x16 sacc;
    #pragma unroll
    for (int j = 0; j < 16; ++j) sacc[j] = 0.0f;

    for (int h = 0; h < NH; ++h) {
        __syncthreads();   // h=0: Wl visible; h>0: previous readers done
        {
            const short8* hb = qs + (size_t)(bq * 16 + h) * 2048;
            #pragma unroll
            for (int cc = 0; cc < 4; ++cc) {
                const int c = wid * 4 + cc;
                gload_lds16(hb + c * 64 + lane,        &QsH[c * 64]);
                gload_lds16(hb + 1024 + c * 64 + lane, &QsL[c * 64]);
            }
        }
        __syncthreads();   // drains vmcnt -> staged data visible

        f32x16 ahh, ahl, alh;   // three independent chains
        #pragma unroll
        for (int j = 0; j < 16; ++j) { ahh[j] = 0.0f; ahl[j] = 0.0f; alh[j] = 0.0f; }

        #pragma unroll
        for (int s = 0; s < 8; ++s) {
            const short8 ah = QsH[uo[s]];
            const short8 al = QsL[uo[s]];
            ahh = __builtin_amdgcn_mfma_f32_32x32x16_bf16(ah, bh[s], ahh, 0, 0, 0);
            ahl = __builtin_amdgcn_mfma_f32_32x32x16_bf16(ah, bl[s], ahl, 0, 0, 0);
            alh = __builtin_amdgcn_mfma_f32_32x32x16_bf16(al, bh[s], alh, 0, 0, 0);
        }

        // epilogue: sacc += w' * relu(hh + hl + lh); Wl read is a broadcast
        #pragma unroll
        for (int j = 0; j < 16; ++j) {
            const int row = wr * 32 + (j & 3) + 8 * (j >> 2) + 4 * hi5;
            const float wv = Wl[row * NH + h];
            const float lg = (ahh[j] + ahl[j]) + alh[j];
            sacc[j] = fmaf(wv, fmaxf(lg, 0.f), sacc[j]);
        }
    }

    // ---- store with causal mask ----
    #pragma unroll
    for (int j = 0; j < 16; ++j) {
        const int q  = qbase + wr * 32 + (j & 3) + 8 * (j >> 2) + 4 * hi5;
        const int kk = kbase + wc * 32 + l31;
        scores[(size_t)q * SK + kk] = (kk <= q) ? sacc[j] : NEG_SENTINEL;
    }
}

// ---------------------------------------------------------------------------
// Shared 2048-key bitonic sort: 256 threads x 8 keys (i = t*8 + r).
//   j <= 4   : register passes
//   j 8..256 : __shfl_xor (lane bits)
//   j >= 512 : LDS, swizzled (phys r ^= t&7; j >= 512 flips bits >= 9)
// Emits the 2048 indices (descending value, ascending index on ties).
// ---------------------------------------------------------------------------
#define REG8(J)                                                            \
    {                                                                      \
        _Pragma("unroll")                                                  \
        for (int r = 0; r < 8; ++r) {                                      \
            if ((r & (J)) == 0) {                                          \
                const int i = (t << 3) | r;                                \
                const bool up = ((i & k) == 0);                            \
                const unsigned long long a = key[r], b = key[r | (J)];     \
                const unsigned long long mx = a > b ? a : b;               \
                const unsigned long long mn = a > b ? b : a;               \
                key[r]       = up ? mx : mn;                               \
                key[r | (J)] = up ? mn : mx;                               \
            }                                                              \
        }                                                                  \
    }

__device__ __forceinline__ void sort2048_emit(
    unsigned long long key[8], unsigned long long* cld,
    float* __restrict__ out_row, const int t)
{
    const int sw8 = t & 7;
    for (int k = 2; k <= 2048; k <<= 1) {
        for (int j = k >> 1; j >= 512; j >>= 1) {
            __syncthreads();
            #pragma unroll
            for (int r = 0; r < 8; ++r) cld[(t << 3) | (r ^ sw8)] = key[r];
            __syncthreads();
            #pragma unroll
            for (int r = 0; r < 8; ++r) {
                const int i = (t << 3) | r;
                const unsigned long long bb = cld[(((t << 3) | (r ^ sw8))) ^ j];
                const bool take_max = (((i & k) == 0) == ((i & j) == 0));
                const bool agtb = key[r] > bb;
                key[r] = (take_max == agtb) ? key[r] : bb;
            }
        }
        {
            const int j0 = (k >> 1) < 256 ? (k >> 1) : 256;
            for (int j = j0; j >= 8; j >>= 1) {
                #pragma unroll
                for (int r = 0; r < 8; ++r) {
                    const int i = (t << 3) | r;
                    const unsigned long long bb =
                        (unsigned long long)__shfl_xor((long long)key[r], j >> 3, 64);
                    const bool take_max = (((i & k) == 0) == ((i & j) == 0));
                    const bool agtb = key[r] > bb;
                    key[r] = (take_max == agtb) ? key[r] : bb;
                }
            }
        }
        if (k > 4) REG8(4)
        if (k > 2) REG8(2)
        REG8(1)
    }

    #pragma unroll
    for (int r2 = 0; r2 < 2; ++r2) {
        float4 o;
        o.x = (float)(4095u - (unsigned int)(key[r2 * 4 + 0] & 0xFFFFFFFFu));
        o.y = (float)(4095u - (unsigned int)(key[r2 * 4 + 1] & 0xFFFFFFFFu));
        o.z = (float)(4095u - (unsigned int)(key[r2 * 4 + 2] & 0xFFFFFFFFu));
        o.w = (float)(4095u - (unsigned int)(key[r2 * 4 + 3] & 0xFFFFFFFFu));
        *(float4*)&out_row[(t << 3) + r2 * 4] = o;
    }
}

// ---------------------------------------------------------------------------
// Kernel 2a: rows 0..2047 — top-2048 == sorted first-2048 prefix (validated
// sentinel-tail argument, round 5). Load prefix directly, sort, emit.
// ---------------------------------------------------------------------------
__global__ __launch_bounds__(256) void topk_prefix_kernel(
    const float* __restrict__ scores,
    float* __restrict__ out_idx)
{
    __shared__ unsigned long long cld[2048];

    const int qrow = blockIdx.x;
    const int t    = threadIdx.x;

    unsigned long long key[8];
    {
        const float* rowp = scores + (size_t)qrow * SK + (t << 3);
        #pragma unroll
        for (int r4 = 0; r4 < 2; ++r4) {
            const float4 v = *(const float4*)(rowp + r4 * 4);
            const float vs[4] = {v.x, v.y, v.z, v.w};
            #pragma unroll
            for (int rr = 0; rr < 4; ++rr) {
                const int r = r4 * 4 + rr;
                const int i = (t << 3) | r;
                const unsigned int b = __float_as_uint(vs[rr]);
                const unsigned int u = (b & 0x80000000u) ? ~b : (b | 0x80000000u);
                key[r] = ((unsigned long long)u << 32) | (unsigned int)(4095 - i);
            }
        }
    }

    sort2048_emit(key, cld, out_idx + (size_t)qrow * TOPK, t);
}

// ---------------------------------------------------------------------------
// Kernel 2b: rows 2048..4095 — binary-search select of the 2048th-largest u,
// stable compaction (value desc, index asc), then the shared 2048-sort.
// ---------------------------------------------------------------------------
__global__ __launch_bounds__(256) void topk_select_kernel(
    const float* __restrict__ scores,
    float* __restrict__ out_idx,
    int row_base)
{
    __shared__ unsigned long long cld[2048];
    __shared__ unsigned int wsum[4];

    const int qrow = row_base + blockIdx.x;
    const int t    = threadIdx.x;
    const int lane = t & 63;
    const int wid  = t >> 6;

    unsigned int u[16];
    {
        const float* rowp = scores + (size_t)qrow * SK + (t << 4);
        #pragma unroll
        for (int r4 = 0; r4 < 4; ++r4) {
            const float4 v = *(const float4*)(rowp + r4 * 4);
            const float vs[4] = {v.x, v.y, v.z, v.w};
            #pragma unroll
            for (int rr = 0; rr < 4; ++rr) {
                const unsigned int b = __float_as_uint(vs[rr]);
                u[r4 * 4 + rr] = (b & 0x80000000u) ? ~b : (b | 0x80000000u);
            }
        }
    }

    // binary search: Tu = 2048th-largest u (valid u >= 0x80000000 > sentinel)
    unsigned int lo = 0x80000000u, hi = 0xFFFFFFFFu;
    while (lo < hi) {
        const unsigned int mid = lo + ((hi - lo) >> 1) + 1u;
        unsigned int c = 0;
        #pragma unroll
        for (int r = 0; r < 16; ++r) c += (u[r] >= mid) ? 1u : 0u;
        #pragma unroll
        for (int d = 32; d >= 1; d >>= 1) c += __shfl_xor(c, d, 64);
        if (lane == 0) wsum[wid] = c;
        __syncthreads();
        const unsigned int tot = wsum[0] + wsum[1] + wsum[2] + wsum[3];
        __syncthreads();
        if (tot >= 2048u) lo = mid; else hi = mid - 1u;
    }
    const unsigned int Tu = lo;

    unsigned int count_gt;
    {
        unsigned int c = 0;
        #pragma unroll
        for (int r = 0; r < 16; ++r) c += (u[r] > Tu) ? 1u : 0u;
        #pragma unroll
        for (int d = 32; d >= 1; d >>= 1) c += __shfl_xor(c, d, 64);
        if (lane == 0) wsum[wid] = c;
        __syncthreads();
        count_gt = wsum[0] + wsum[1] + wsum[2] + wsum[3];
        __syncthreads();
    }
    const unsigned int need = 2048u - count_gt;

    // stable exclusive prefixes (ascending index) of (gt, eq)
    unsigned int gtb[16], eqb[16];
    unsigned int cgt = 0, ceq = 0;
    #pragma unroll
    for (int r = 0; r < 16; ++r) {
        gtb[r] = cgt; eqb[r] = ceq;
        cgt += (u[r] > Tu) ? 1u : 0u;
        ceq += (u[r] == Tu) ? 1u : 0u;
    }
    unsigned int pack = (cgt << 16) | ceq;
    unsigned int inc = pack;
    #pragma unroll
    for (int d = 1; d < 64; d <<= 1) {
        const unsigned int v = __shfl_up(inc, d, 64);
        if (lane >= d) inc += v;
    }
    const unsigned int ex = inc - pack;
    if (lane == 63) wsum[wid] = inc;
    __syncthreads();
    unsigned int wex = 0;
    #pragma unroll
    for (int ww = 0; ww < 4; ++ww) wex += (ww < wid) ? wsum[ww] : 0u;
    const unsigned int gt0 = (wex >> 16) + (ex >> 16);
    const unsigned int eq0 = (wex & 0xFFFFu) + (ex & 0xFFFFu);

    // compact selected 2048 keys into cld
    #pragma unroll
    for (int r = 0; r < 16; ++r) {
        const unsigned int g = gt0 + gtb[r];
        const unsigned int e = eq0 + eqb[r];
        const int i = (t << 4) | r;
        const unsigned long long kk =
            ((unsigned long long)u[r] << 32) | (unsigned int)(4095 - i);
        if (u[r] > Tu) {
            cld[g + (e < need ? e : need)] = kk;
        } else if (u[r] == Tu && e < need) {
            cld[g + e] = kk;
        }
    }
    __syncthreads();

    unsigned long long key[8];
    #pragma unroll
    for (int r = 0; r < 8; ++r) key[r] = cld[(t << 3) | r];

    sort2048_emit(key, cld, out_idx + (size_t)qrow * TOPK, t);
}

extern "C" void kernel_launch(void* const* d_in, const int* in_sizes, int n_in,
                              void* d_out, int out_size, void* d_ws, size_t ws_size,
                              hipStream_t stream) {
    const float* q = (const float*)d_in[0];
    const float* k = (const float*)d_in[1];
    const float* w = (const float*)d_in[2];

    float* out        = (float*)d_out;
    float* out_topk   = out;
    float* out_scores = out + (size_t)SQ * TOPK;

    short8* qs = (ws_size >= QS_BYTES) ? (short8*)d_ws : (short8*)out_topk;

    split_q_kernel<<<SQ * NH * 16 / 256, 256, 0, stream>>>(q, qs);

    scores_kernel<<<dim3(SK / TK, SQ / TQ), 256, 0, stream>>>(qs, k, w, out_scores);

    topk_prefix_kernel<<<2048, 256, 0, stream>>>(out_scores, out_topk);
    topk_select_kernel<<<2048, 256, 0, stream>>>(out_scores, out_topk, 2048);
}

// Round 13
// 335.454 us; speedup vs baseline: 1.0114x; 1.0114x over previous
//
#include <hip/hip_runtime.h>
#include <cmath>

#define SQ 4096
#define SK 4096
#define NH 16
#define DH 128
#define TQ 64
#define TK 64
#define TOPK 2048
#define NEG_SENTINEL (-3.0e38f)

typedef __attribute__((ext_vector_type(8))) short short8;
typedef __attribute__((ext_vector_type(4))) float f32x4;

#define QS_BYTES ((size_t)64 * 16 * 2 * 1024 * 16)   // [qtile][head][part][unit16B]

// Split f32 x into bf16 hi + bf16 lo (truncation split; residual exact).
__device__ __forceinline__ void cvt8(const float4 x0, const float4 x1,
                                     short8& hv, short8& lv) {
    const float xs[8] = {x0.x, x0.y, x0.z, x0.w, x1.x, x1.y, x1.z, x1.w};
    #pragma unroll
    for (int j = 0; j < 8; ++j) {
        const unsigned int b = __float_as_uint(xs[j]);
        const float hf = __uint_as_float(b & 0xFFFF0000u);
        const float r = xs[j] - hf;
        hv[j] = (short)(b >> 16);
        lv[j] = (short)(__float_as_uint(r) >> 16);
    }
}

__device__ __forceinline__ void gload_lds16(const void* g, void* l) {
    __builtin_amdgcn_global_load_lds(
        (const __attribute__((address_space(1))) unsigned int*)g,
        (__attribute__((address_space(3))) unsigned int*)l,
        16, 0, 0);
}

// ---------------------------------------------------------------------------
// Kernel 0: pre-split Q (validated, unchanged).
// ---------------------------------------------------------------------------
__global__ __launch_bounds__(256) void split_q_kernel(
    const float* __restrict__ qg,    // [SQ][NH][DH]
    short8* __restrict__ qs)         // [64][16][2][1024] 16B units
{
    const int gidx = blockIdx.x * 256 + threadIdx.x;   // [row][h][c]
    const int c   = gidx & 15;
    const int h   = (gidx >> 4) & 15;
    const int row = gidx >> 8;
    const size_t gb = ((size_t)row * NH + h) * DH + c * 8;
    const float4 x0 = *(const float4*)&qg[gb];
    const float4 x1 = *(const float4*)&qg[gb + 4];
    short8 hv, lv;
    cvt8(x0, x1, hv, lv);
    const int tile = row >> 6;
    const int r    = row & 63;
    const int u    = c * 64 + (r ^ (c & 7));
    const size_t base = (size_t)(tile * 16 + h) * 2048;
    qs[base + u]        = hv;
    qs[base + 1024 + u] = lv;
}

// ---------------------------------------------------------------------------
// Kernel 1: scores — round-10 16x16 3-term structure (validated 135.7us)
// + DOUBLE-BUFFERED Q prefetch: head h+1's global_load_lds issued BEFORE
// head h's compute, ONE barrier per head. The vmcnt(0) drain at the barrier
// lands after ~230cyc of MFMA issue instead of immediately after the loads.
// LDS = 2x32KB + 4KB = 68KB -> 2 blocks/CU (same effective waves as before).
// ---------------------------------------------------------------------------
__global__ __launch_bounds__(256, 2) void scores_kernel(
    const short8* __restrict__ qs,   // pre-split Q
    const float* __restrict__ kg,    // [SK][DH]
    const float* __restrict__ wg,    // [SQ][NH]
    float* __restrict__ scores)      // [SQ][SK]
{
    const int bk = blockIdx.x;
    const int bq = blockIdx.y;
    const int qbase = bq * TQ;
    const int kbase = bk * TK;
    const int tid = threadIdx.x;

    if (bk > bq) {
        const float4 minf = make_float4(NEG_SENTINEL, NEG_SENTINEL, NEG_SENTINEL, NEG_SENTINEL);
        #pragma unroll
        for (int it = 0; it < 4; ++it) {
            int idx = it * 256 + tid;
            int r  = idx >> 4;
            int c4 = idx & 15;
            *(float4*)&scores[(size_t)(qbase + r) * SK + kbase + (c4 << 2)] = minf;
        }
        return;
    }

    __shared__ short8 QsH[2][1024], QsL[2][1024];   // 64KB (double-buffered)
    __shared__ float  Wl[TQ * NH];                  // 4KB

    const int lane = tid & 63;
    const int wid  = tid >> 6;
    const int wr   = wid >> 1;
    const int wc   = wid & 1;
    const int l15  = lane & 15;
    const int l4   = lane >> 4;

    #pragma unroll
    for (int it = 0; it < 4; ++it) {
        const int i = tid + it * 256;
        Wl[i] = wg[(size_t)qbase * NH + i] * 0.08838834764831845f;
    }

    // ---- K fragments in registers (once per block) ----
    short8 bh[2][4], bl[2][4];
    #pragma unroll
    for (int ni = 0; ni < 2; ++ni)
        #pragma unroll
        for (int s = 0; s < 4; ++s) {
            const int key = kbase + wc * 32 + ni * 16 + l15;
            const int c   = s * 4 + l4;
            const float4 x0 = *(const float4*)&kg[(size_t)key * DH + c * 8];
            const float4 x1 = *(const float4*)&kg[(size_t)key * DH + c * 8 + 4];
            cvt8(x0, x1, bh[ni][s], bl[ni][s]);
        }

    f32x4 sacc[2][2];
    #pragma unroll
    for (int mi = 0; mi < 2; ++mi)
        #pragma unroll
        for (int ni = 0; ni < 2; ++ni) sacc[mi][ni] = (f32x4){0.f, 0.f, 0.f, 0.f};

    const short8* qt = qs + (size_t)bq * 16 * 2048;

    // ---- prologue: stage head 0 into buffer 0 ----
    #pragma unroll
    for (int cc = 0; cc < 4; ++cc) {
        const int c = wid * 4 + cc;
        gload_lds16(qt + c * 64 + lane,        &QsH[0][c * 64]);
        gload_lds16(qt + 1024 + c * 64 + lane, &QsL[0][c * 64]);
    }
    __syncthreads();   // buf0 + Wl ready

    for (int h = 0; h < NH; ++h) {
        const int cur = h & 1;

        // prefetch head h+1 into the other buffer (issued before compute)
        if (h + 1 < NH) {
            const short8* hb = qt + (size_t)(h + 1) * 2048;
            #pragma unroll
            for (int cc = 0; cc < 4; ++cc) {
                const int c = wid * 4 + cc;
                gload_lds16(hb + c * 64 + lane,        &QsH[cur ^ 1][c * 64]);
                gload_lds16(hb + 1024 + c * 64 + lane, &QsL[cur ^ 1][c * 64]);
            }
        }

        f32x4 lac[2][2];
        #pragma unroll
        for (int mi = 0; mi < 2; ++mi)
            #pragma unroll
            for (int ni = 0; ni < 2; ++ni) lac[mi][ni] = (f32x4){0.f, 0.f, 0.f, 0.f};

        #pragma unroll
        for (int s = 0; s < 4; ++s) {
            short8 ah[2], al[2];
            #pragma unroll
            for (int mi = 0; mi < 2; ++mi) {
                const int row = wr * 32 + mi * 16 + l15;
                const int c   = s * 4 + l4;
                const int u   = c * 64 + (row ^ (c & 7));
                ah[mi] = QsH[cur][u];
                al[mi] = QsL[cur][u];
            }
            #pragma unroll
            for (int mi = 0; mi < 2; ++mi)
                #pragma unroll
                for (int ni = 0; ni < 2; ++ni) {
                    lac[mi][ni] = __builtin_amdgcn_mfma_f32_16x16x32_bf16(ah[mi], bh[ni][s], lac[mi][ni], 0, 0, 0);
                    lac[mi][ni] = __builtin_amdgcn_mfma_f32_16x16x32_bf16(ah[mi], bl[ni][s], lac[mi][ni], 0, 0, 0);
                    lac[mi][ni] = __builtin_amdgcn_mfma_f32_16x16x32_bf16(al[mi], bh[ni][s], lac[mi][ni], 0, 0, 0);
                }
        }

        float wv[2][4];
        #pragma unroll
        for (int mi = 0; mi < 2; ++mi)
            #pragma unroll
            for (int j = 0; j < 4; ++j) {
                const int row = wr * 32 + mi * 16 + l4 * 4 + j;
                wv[mi][j] = Wl[row * NH + h];
            }
        #pragma unroll
        for (int mi = 0; mi < 2; ++mi)
            #pragma unroll
            for (int ni = 0; ni < 2; ++ni)
                #pragma unroll
                for (int j = 0; j < 4; ++j)
                    sacc[mi][ni][j] = fmaf(wv[mi][j], fmaxf(lac[mi][ni][j], 0.f), sacc[mi][ni][j]);

        __syncthreads();   // prefetch landed (had full compute to cover) +
                           // all waves done reading buf[cur]
    }

    #pragma unroll
    for (int mi = 0; mi < 2; ++mi)
        #pragma unroll
        for (int ni = 0; ni < 2; ++ni)
            #pragma unroll
            for (int j = 0; j < 4; ++j) {
                const int q  = qbase + wr * 32 + mi * 16 + l4 * 4 + j;
                const int kk = kbase + wc * 32 + ni * 16 + l15;
                scores[(size_t)q * SK + kk] = (kk <= q) ? sacc[mi][ni][j] : NEG_SENTINEL;
            }
}

// ---------------------------------------------------------------------------
// Shared 2048-key bitonic sort (validated): 256 thr x 8 keys (i = t*8 + r).
// ---------------------------------------------------------------------------
#define REG8(J)                                                            \
    {                                                                      \
        _Pragma("unroll")                                                  \
        for (int r = 0; r < 8; ++r) {                                      \
            if ((r & (J)) == 0) {                                          \
                const int i = (t << 3) | r;                                \
                const bool up = ((i & k) == 0);                            \
                const unsigned long long a = key[r], b = key[r | (J)];     \
                const unsigned long long mx = a > b ? a : b;               \
                const unsigned long long mn = a > b ? b : a;               \
                key[r]       = up ? mx : mn;                               \
                key[r | (J)] = up ? mn : mx;                               \
            }                                                              \
        }                                                                  \
    }

__device__ __forceinline__ void sort2048_emit(
    unsigned long long key[8], unsigned long long* cld,
    float* __restrict__ out_row, const int t)
{
    const int sw8 = t & 7;
    for (int k = 2; k <= 2048; k <<= 1) {
        for (int j = k >> 1; j >= 512; j >>= 1) {
            __syncthreads();
            #pragma unroll
            for (int r = 0; r < 8; ++r) cld[(t << 3) | (r ^ sw8)] = key[r];
            __syncthreads();
            #pragma unroll
            for (int r = 0; r < 8; ++r) {
                const int i = (t << 3) | r;
                const unsigned long long bb = cld[(((t << 3) | (r ^ sw8))) ^ j];
                const bool take_max = (((i & k) == 0) == ((i & j) == 0));
                const bool agtb = key[r] > bb;
                key[r] = (take_max == agtb) ? key[r] : bb;
            }
        }
        {
            const int j0 = (k >> 1) < 256 ? (k >> 1) : 256;
            for (int j = j0; j >= 8; j >>= 1) {
                #pragma unroll
                for (int r = 0; r < 8; ++r) {
                    const int i = (t << 3) | r;
                    const unsigned long long bb =
                        (unsigned long long)__shfl_xor((long long)key[r], j >> 3, 64);
                    const bool take_max = (((i & k) == 0) == ((i & j) == 0));
                    const bool agtb = key[r] > bb;
                    key[r] = (take_max == agtb) ? key[r] : bb;
                }
            }
        }
        if (k > 4) REG8(4)
        if (k > 2) REG8(2)
        REG8(1)
    }

    #pragma unroll
    for (int r2 = 0; r2 < 2; ++r2) {
        float4 o;
        o.x = (float)(4095u - (unsigned int)(key[r2 * 4 + 0] & 0xFFFFFFFFu));
        o.y = (float)(4095u - (unsigned int)(key[r2 * 4 + 1] & 0xFFFFFFFFu));
        o.z = (float)(4095u - (unsigned int)(key[r2 * 4 + 2] & 0xFFFFFFFFu));
        o.w = (float)(4095u - (unsigned int)(key[r2 * 4 + 3] & 0xFFFFFFFFu));
        *(float4*)&out_row[(t << 3) + r2 * 4] = o;
    }
}

// ---------------------------------------------------------------------------
// Kernel 2: merged topk over all 4096 rows.
//   row < 2048 : top-2048 == sorted first-2048 prefix (sentinel-tail proof).
//   row >= 2048: binary-search select (with exact-count early exit) + stable
//                compaction (value desc, index asc) + shared 2048-sort.
// ---------------------------------------------------------------------------
__global__ __launch_bounds__(256) void topk_merged_kernel(
    const float* __restrict__ scores,
    float* __restrict__ out_idx)
{
    __shared__ unsigned long long cld[2048];
    __shared__ unsigned int wsum[4];

    const int qrow = blockIdx.x;
    const int t    = threadIdx.x;
    const int lane = t & 63;
    const int wid  = t >> 6;

    unsigned long long key[8];

    if (qrow < 2048) {
        // ---- prefix path: load first 2048, transform, sort ----
        const float* rowp = scores + (size_t)qrow * SK + (t << 3);
        #pragma unroll
        for (int r4 = 0; r4 < 2; ++r4) {
            const float4 v = *(const float4*)(rowp + r4 * 4);
            const float vs[4] = {v.x, v.y, v.z, v.w};
            #pragma unroll
            for (int rr = 0; rr < 4; ++rr) {
                const int r = r4 * 4 + rr;
                const int i = (t << 3) | r;
                const unsigned int b = __float_as_uint(vs[rr]);
                const unsigned int u = (b & 0x80000000u) ? ~b : (b | 0x80000000u);
                key[r] = ((unsigned long long)u << 32) | (unsigned int)(4095 - i);
            }
        }
    } else {
        // ---- select path ----
        unsigned int u[16];
        {
            const float* rowp = scores + (size_t)qrow * SK + (t << 4);
            #pragma unroll
            for (int r4 = 0; r4 < 4; ++r4) {
                const float4 v = *(const float4*)(rowp + r4 * 4);
                const float vs[4] = {v.x, v.y, v.z, v.w};
                #pragma unroll
                for (int rr = 0; rr < 4; ++rr) {
                    const unsigned int b = __float_as_uint(vs[rr]);
                    u[r4 * 4 + rr] = (b & 0x80000000u) ? ~b : (b | 0x80000000u);
                }
            }
        }

        // binary search with exact-count early exit
        unsigned int lo = 0x80000000u, hi = 0xFFFFFFFFu;
        unsigned int Tu = 0, count_gt = 0;
        int exact = 0;
        while (lo < hi) {
            const unsigned int mid = lo + ((hi - lo) >> 1) + 1u;
            unsigned int c = 0;
            #pragma unroll
            for (int r = 0; r < 16; ++r) c += (u[r] >= mid) ? 1u : 0u;
            #pragma unroll
            for (int d = 32; d >= 1; d >>= 1) c += __shfl_xor(c, d, 64);
            if (lane == 0) wsum[wid] = c;
            __syncthreads();
            const unsigned int tot = wsum[0] + wsum[1] + wsum[2] + wsum[3];
            __syncthreads();
            if (tot == 2048u) {             // top set = {u >= mid}, tie-free
                Tu = mid - 1u;              // "u > Tu" <=> "u >= mid"
                count_gt = 2048u;
                exact = 1;
                break;
            }
            if (tot > 2048u) lo = mid; else hi = mid - 1u;
        }
        if (!exact) {
            Tu = lo;
            unsigned int c = 0;
            #pragma unroll
            for (int r = 0; r < 16; ++r) c += (u[r] > Tu) ? 1u : 0u;
            #pragma unroll
            for (int d = 32; d >= 1; d >>= 1) c += __shfl_xor(c, d, 64);
            if (lane == 0) wsum[wid] = c;
            __syncthreads();
            count_gt = wsum[0] + wsum[1] + wsum[2] + wsum[3];
            __syncthreads();
        }
        const unsigned int need = 2048u - count_gt;

        // stable exclusive prefixes (ascending index) of (gt, eq)
        unsigned int gtb[16], eqb[16];
        unsigned int cgt = 0, ceq = 0;
        #pragma unroll
        for (int r = 0; r < 16; ++r) {
            gtb[r] = cgt; eqb[r] = ceq;
            cgt += (u[r] > Tu) ? 1u : 0u;
            ceq += (u[r] == Tu) ? 1u : 0u;
        }
        unsigned int pack = (cgt << 16) | ceq;
        unsigned int inc = pack;
        #pragma unroll
        for (int d = 1; d < 64; d <<= 1) {
            const unsigned int v = __shfl_up(inc, d, 64);
            if (lane >= d) inc += v;
        }
        const unsigned int ex = inc - pack;
        if (lane == 63) wsum[wid] = inc;
        __syncthreads();
        unsigned int wex = 0;
        #pragma unroll
        for (int ww = 0; ww < 4; ++ww) wex += (ww < wid) ? wsum[ww] : 0u;
        const unsigned int gt0 = (wex >> 16) + (ex >> 16);
        const unsigned int eq0 = (wex & 0xFFFFu) + (ex & 0xFFFFu);

        // compact selected 2048 keys into cld
        #pragma unroll
        for (int r = 0; r < 16; ++r) {
            const unsigned int g = gt0 + gtb[r];
            const unsigned int e = eq0 + eqb[r];
            const int i = (t << 4) | r;
            const unsigned long long kk =
                ((unsigned long long)u[r] << 32) | (unsigned int)(4095 - i);
            if (u[r] > Tu) {
                cld[g + (e < need ? e : need)] = kk;
            } else if (u[r] == Tu && e < need) {
                cld[g + e] = kk;
            }
        }
        __syncthreads();

        #pragma unroll
        for (int r = 0; r < 8; ++r) key[r] = cld[(t << 3) | r];
    }

    sort2048_emit(key, cld, out_idx + (size_t)qrow * TOPK, t);
}

extern "C" void kernel_launch(void* const* d_in, const int* in_sizes, int n_in,
                              void* d_out, int out_size, void* d_ws, size_t ws_size,
                              hipStream_t stream) {
    const float* q = (const float*)d_in[0];
    const float* k = (const float*)d_in[1];
    const float* w = (const float*)d_in[2];

    float* out        = (float*)d_out;
    float* out_topk   = out;
    float* out_scores = out + (size_t)SQ * TOPK;

    short8* qs = (ws_size >= QS_BYTES) ? (short8*)d_ws : (short8*)out_topk;

    split_q_kernel<<<SQ * NH * 16 / 256, 256, 0, stream>>>(q, qs);

    scores_kernel<<<dim3(SK / TK, SQ / TQ), 256, 0, stream>>>(qs, k, w, out_scores);

    topk_merged_kernel<<<SQ, 256, 0, stream>>>(out_scores, out_topk);
}

// Round 14
// 324.797 us; speedup vs baseline: 1.0445x; 1.0328x over previous
//
#include <hip/hip_runtime.h>
#include <cmath>

#define SQ 4096
#define SK 4096
#define NH 16
#define DH 128
#define TOPK 2048
#define NEG_SENTINEL (-3.0e38f)

typedef __attribute__((ext_vector_type(8))) short short8;
typedef __attribute__((ext_vector_type(4))) float f32x4;

#define QS_BYTES ((size_t)64 * 16 * 2 * 1024 * 16)   // [qtile][head][part][unit16B]

// Split f32 x into bf16 hi + bf16 lo (truncation split; residual exact).
__device__ __forceinline__ void cvt8(const float4 x0, const float4 x1,
                                     short8& hv, short8& lv) {
    const float xs[8] = {x0.x, x0.y, x0.z, x0.w, x1.x, x1.y, x1.z, x1.w};
    #pragma unroll
    for (int j = 0; j < 8; ++j) {
        const unsigned int b = __float_as_uint(xs[j]);
        const float hf = __uint_as_float(b & 0xFFFF0000u);
        const float r = xs[j] - hf;
        hv[j] = (short)(b >> 16);
        lv[j] = (short)(__float_as_uint(r) >> 16);
    }
}

__device__ __forceinline__ void gload_lds16(const void* g, void* l) {
    __builtin_amdgcn_global_load_lds(
        (const __attribute__((address_space(1))) unsigned int*)g,
        (__attribute__((address_space(3))) unsigned int*)l,
        16, 0, 0);
}

// ---------------------------------------------------------------------------
// Kernel 0: pre-split Q (validated, unchanged).
// ---------------------------------------------------------------------------
__global__ __launch_bounds__(256) void split_q_kernel(
    const float* __restrict__ qg,    // [SQ][NH][DH]
    short8* __restrict__ qs)         // [64][16][2][1024] 16B units
{
    const int gidx = blockIdx.x * 256 + threadIdx.x;   // [row][h][c]
    const int c   = gidx & 15;
    const int h   = (gidx >> 4) & 15;
    const int row = gidx >> 8;
    const size_t gb = ((size_t)row * NH + h) * DH + c * 8;
    const float4 x0 = *(const float4*)&qg[gb];
    const float4 x1 = *(const float4*)&qg[gb + 4];
    short8 hv, lv;
    cvt8(x0, x1, hv, lv);
    const int tile = row >> 6;
    const int r    = row & 63;
    const int u    = c * 64 + (r ^ (c & 7));
    const size_t base = (size_t)(tile * 16 + h) * 2048;
    qs[base + u]        = hv;
    qs[base + 1024 + u] = lv;
}

// ---------------------------------------------------------------------------
// Kernel 1: scores — round-10 per-wave structure (validated 135.7us), block
// widened to 64q x 128k with 512 threads (8 waves, 2x4). Q staging (32KB/head)
// now feeds 2x the MFMA work -> per-CU staging bytes and the per-head
// vmcnt-drain stall halve. Per-wave code identical to round 10; LDS still
// 36KB; resident waves/CU unchanged.
// ---------------------------------------------------------------------------
__global__ __launch_bounds__(512, 4) void scores_kernel(
    const short8* __restrict__ qs,   // pre-split Q
    const float* __restrict__ kg,    // [SK][DH]
    const float* __restrict__ wg,    // [SQ][NH]
    float* __restrict__ scores)      // [SQ][SK]
{
    const int kgi = blockIdx.x;          // 128-wide k group
    const int bq  = blockIdx.y;
    const int qbase  = bq * 64;
    const int kbase0 = kgi * 128;
    const int tid = threadIdx.x;

    if (kbase0 > qbase + 63) {
        // fully masked 64x128 region
        const float4 minf = make_float4(NEG_SENTINEL, NEG_SENTINEL, NEG_SENTINEL, NEG_SENTINEL);
        #pragma unroll
        for (int it = 0; it < 4; ++it) {
            const int idx = it * 512 + tid;   // 0..2047 float4
            const int r  = idx >> 5;          // 32 float4 per row
            const int c4 = idx & 31;
            *(float4*)&scores[(size_t)(qbase + r) * SK + kbase0 + (c4 << 2)] = minf;
        }
        return;
    }

    __shared__ short8 QsH[1024], QsL[1024];   // 16KB + 16KB
    __shared__ float  Wl[64 * NH];            // 4KB

    const int lane = tid & 63;
    const int wid  = tid >> 6;     // 0..7
    const int wr   = wid >> 2;     // q-half (0..1)
    const int wc   = wid & 3;      // k-quarter (0..3)
    const int l15  = lane & 15;
    const int l4   = lane >> 4;

    #pragma unroll
    for (int it = 0; it < 2; ++it) {
        const int i = tid + it * 512;
        Wl[i] = wg[(size_t)qbase * NH + i] * 0.08838834764831845f;
    }

    // ---- K fragments in registers (once per block) ----
    short8 bh[2][4], bl[2][4];
    #pragma unroll
    for (int ni = 0; ni < 2; ++ni)
        #pragma unroll
        for (int s = 0; s < 4; ++s) {
            const int key = kbase0 + wc * 32 + ni * 16 + l15;
            const int c   = s * 4 + l4;
            const float4 x0 = *(const float4*)&kg[(size_t)key * DH + c * 8];
            const float4 x1 = *(const float4*)&kg[(size_t)key * DH + c * 8 + 4];
            cvt8(x0, x1, bh[ni][s], bl[ni][s]);
        }

    f32x4 sacc[2][2];
    #pragma unroll
    for (int mi = 0; mi < 2; ++mi)
        #pragma unroll
        for (int ni = 0; ni < 2; ++ni) sacc[mi][ni] = (f32x4){0.f, 0.f, 0.f, 0.f};

    const short8* qt = qs + (size_t)bq * 16 * 2048;

    for (int h = 0; h < NH; ++h) {
        __syncthreads();   // h=0: Wl visible; h>0: previous readers done
        {
            const short8* hb = qt + (size_t)h * 2048;
            #pragma unroll
            for (int cc = 0; cc < 2; ++cc) {
                const int c = wid * 2 + cc;
                gload_lds16(hb + c * 64 + lane,        &QsH[c * 64]);
                gload_lds16(hb + 1024 + c * 64 + lane, &QsL[c * 64]);
            }
        }
        __syncthreads();   // drains vmcnt -> staged data visible

        f32x4 lac[2][2];
        #pragma unroll
        for (int mi = 0; mi < 2; ++mi)
            #pragma unroll
            for (int ni = 0; ni < 2; ++ni) lac[mi][ni] = (f32x4){0.f, 0.f, 0.f, 0.f};

        #pragma unroll
        for (int s = 0; s < 4; ++s) {
            short8 ah[2], al[2];
            #pragma unroll
            for (int mi = 0; mi < 2; ++mi) {
                const int row = wr * 32 + mi * 16 + l15;
                const int c   = s * 4 + l4;
                const int u   = c * 64 + (row ^ (c & 7));
                ah[mi] = QsH[u];
                al[mi] = QsL[u];
            }
            #pragma unroll
            for (int mi = 0; mi < 2; ++mi)
                #pragma unroll
                for (int ni = 0; ni < 2; ++ni) {
                    lac[mi][ni] = __builtin_amdgcn_mfma_f32_16x16x32_bf16(ah[mi], bh[ni][s], lac[mi][ni], 0, 0, 0);
                    lac[mi][ni] = __builtin_amdgcn_mfma_f32_16x16x32_bf16(ah[mi], bl[ni][s], lac[mi][ni], 0, 0, 0);
                    lac[mi][ni] = __builtin_amdgcn_mfma_f32_16x16x32_bf16(al[mi], bh[ni][s], lac[mi][ni], 0, 0, 0);
                }
        }

        float wv[2][4];
        #pragma unroll
        for (int mi = 0; mi < 2; ++mi)
            #pragma unroll
            for (int j = 0; j < 4; ++j) {
                const int row = wr * 32 + mi * 16 + l4 * 4 + j;
                wv[mi][j] = Wl[row * NH + h];
            }
        #pragma unroll
        for (int mi = 0; mi < 2; ++mi)
            #pragma unroll
            for (int ni = 0; ni < 2; ++ni)
                #pragma unroll
                for (int j = 0; j < 4; ++j)
                    sacc[mi][ni][j] = fmaf(wv[mi][j], fmaxf(lac[mi][ni][j], 0.f), sacc[mi][ni][j]);
    }

    #pragma unroll
    for (int mi = 0; mi < 2; ++mi)
        #pragma unroll
        for (int ni = 0; ni < 2; ++ni)
            #pragma unroll
            for (int j = 0; j < 4; ++j) {
                const int q  = qbase + wr * 32 + mi * 16 + l4 * 4 + j;
                const int kk = kbase0 + wc * 32 + ni * 16 + l15;
                scores[(size_t)q * SK + kk] = (kk <= q) ? sacc[mi][ni][j] : NEG_SENTINEL;
            }
}

// ---------------------------------------------------------------------------
// Shared 2048-key bitonic sort (validated): 256 thr x 8 keys (i = t*8 + r).
// ---------------------------------------------------------------------------
#define REG8(J)                                                            \
    {                                                                      \
        _Pragma("unroll")                                                  \
        for (int r = 0; r < 8; ++r) {                                      \
            if ((r & (J)) == 0) {                                          \
                const int i = (t << 3) | r;                                \
                const bool up = ((i & k) == 0);                            \
                const unsigned long long a = key[r], b = key[r | (J)];     \
                const unsigned long long mx = a > b ? a : b;               \
                const unsigned long long mn = a > b ? b : a;               \
                key[r]       = up ? mx : mn;                               \
                key[r | (J)] = up ? mn : mx;                               \
            }                                                              \
        }                                                                  \
    }

__device__ __forceinline__ void sort2048_emit(
    unsigned long long key[8], unsigned long long* cld,
    float* __restrict__ out_row, const int t)
{
    const int sw8 = t & 7;
    for (int k = 2; k <= 2048; k <<= 1) {
        for (int j = k >> 1; j >= 512; j >>= 1) {
            __syncthreads();
            #pragma unroll
            for (int r = 0; r < 8; ++r) cld[(t << 3) | (r ^ sw8)] = key[r];
            __syncthreads();
            #pragma unroll
            for (int r = 0; r < 8; ++r) {
                const int i = (t << 3) | r;
                const unsigned long long bb = cld[(((t << 3) | (r ^ sw8))) ^ j];
                const bool take_max = (((i & k) == 0) == ((i & j) == 0));
                const bool agtb = key[r] > bb;
                key[r] = (take_max == agtb) ? key[r] : bb;
            }
        }
        {
            const int j0 = (k >> 1) < 256 ? (k >> 1) : 256;
            for (int j = j0; j >= 8; j >>= 1) {
                #pragma unroll
                for (int r = 0; r < 8; ++r) {
                    const int i = (t << 3) | r;
                    const unsigned long long bb =
                        (unsigned long long)__shfl_xor((long long)key[r], j >> 3, 64);
                    const bool take_max = (((i & k) == 0) == ((i & j) == 0));
                    const bool agtb = key[r] > bb;
                    key[r] = (take_max == agtb) ? key[r] : bb;
                }
            }
        }
        if (k > 4) REG8(4)
        if (k > 2) REG8(2)
        REG8(1)
    }

    #pragma unroll
    for (int r2 = 0; r2 < 2; ++r2) {
        float4 o;
        o.x = (float)(4095u - (unsigned int)(key[r2 * 4 + 0] & 0xFFFFFFFFu));
        o.y = (float)(4095u - (unsigned int)(key[r2 * 4 + 1] & 0xFFFFFFFFu));
        o.z = (float)(4095u - (unsigned int)(key[r2 * 4 + 2] & 0xFFFFFFFFu));
        o.w = (float)(4095u - (unsigned int)(key[r2 * 4 + 3] & 0xFFFFFFFFu));
        *(float4*)&out_row[(t << 3) + r2 * 4] = o;
    }
}

// ---------------------------------------------------------------------------
// Kernel 2: merged topk over all 4096 rows (validated round 13, unchanged).
// ---------------------------------------------------------------------------
__global__ __launch_bounds__(256) void topk_merged_kernel(
    const float* __restrict__ scores,
    float* __restrict__ out_idx)
{
    __shared__ unsigned long long cld[2048];
    __shared__ unsigned int wsum[4];

    const int qrow = blockIdx.x;
    const int t    = threadIdx.x;
    const int lane = t & 63;
    const int wid  = t >> 6;

    unsigned long long key[8];

    if (qrow < 2048) {
        const float* rowp = scores + (size_t)qrow * SK + (t << 3);
        #pragma unroll
        for (int r4 = 0; r4 < 2; ++r4) {
            const float4 v = *(const float4*)(rowp + r4 * 4);
            const float vs[4] = {v.x, v.y, v.z, v.w};
            #pragma unroll
            for (int rr = 0; rr < 4; ++rr) {
                const int r = r4 * 4 + rr;
                const int i = (t << 3) | r;
                const unsigned int b = __float_as_uint(vs[rr]);
                const unsigned int u = (b & 0x80000000u) ? ~b : (b | 0x80000000u);
                key[r] = ((unsigned long long)u << 32) | (unsigned int)(4095 - i);
            }
        }
    } else {
        unsigned int u[16];
        {
            const float* rowp = scores + (size_t)qrow * SK + (t << 4);
            #pragma unroll
            for (int r4 = 0; r4 < 4; ++r4) {
                const float4 v = *(const float4*)(rowp + r4 * 4);
                const float vs[4] = {v.x, v.y, v.z, v.w};
                #pragma unroll
                for (int rr = 0; rr < 4; ++rr) {
                    const unsigned int b = __float_as_uint(vs[rr]);
                    u[r4 * 4 + rr] = (b & 0x80000000u) ? ~b : (b | 0x80000000u);
                }
            }
        }

        unsigned int lo = 0x80000000u, hi = 0xFFFFFFFFu;
        unsigned int Tu = 0, count_gt = 0;
        int exact = 0;
        while (lo < hi) {
            const unsigned int mid = lo + ((hi - lo) >> 1) + 1u;
            unsigned int c = 0;
            #pragma unroll
            for (int r = 0; r < 16; ++r) c += (u[r] >= mid) ? 1u : 0u;
            #pragma unroll
            for (int d = 32; d >= 1; d >>= 1) c += __shfl_xor(c, d, 64);
            if (lane == 0) wsum[wid] = c;
            __syncthreads();
            const unsigned int tot = wsum[0] + wsum[1] + wsum[2] + wsum[3];
            __syncthreads();
            if (tot == 2048u) {
                Tu = mid - 1u;
                count_gt = 2048u;
                exact = 1;
                break;
            }
            if (tot > 2048u) lo = mid; else hi = mid - 1u;
        }
        if (!exact) {
            Tu = lo;
            unsigned int c = 0;
            #pragma unroll
            for (int r = 0; r < 16; ++r) c += (u[r] > Tu) ? 1u : 0u;
            #pragma unroll
            for (int d = 32; d >= 1; d >>= 1) c += __shfl_xor(c, d, 64);
            if (lane == 0) wsum[wid] = c;
            __syncthreads();
            count_gt = wsum[0] + wsum[1] + wsum[2] + wsum[3];
            __syncthreads();
        }
        const unsigned int need = 2048u - count_gt;

        unsigned int gtb[16], eqb[16];
        unsigned int cgt = 0, ceq = 0;
        #pragma unroll
        for (int r = 0; r < 16; ++r) {
            gtb[r] = cgt; eqb[r] = ceq;
            cgt += (u[r] > Tu) ? 1u : 0u;
            ceq += (u[r] == Tu) ? 1u : 0u;
        }
        unsigned int pack = (cgt << 16) | ceq;
        unsigned int inc = pack;
        #pragma unroll
        for (int d = 1; d < 64; d <<= 1) {
            const unsigned int v = __shfl_up(inc, d, 64);
            if (lane >= d) inc += v;
        }
        const unsigned int ex = inc - pack;
        if (lane == 63) wsum[wid] = inc;
        __syncthreads();
        unsigned int wex = 0;
        #pragma unroll
        for (int ww = 0; ww < 4; ++ww) wex += (ww < wid) ? wsum[ww] : 0u;
        const unsigned int gt0 = (wex >> 16) + (ex >> 16);
        const unsigned int eq0 = (wex & 0xFFFFu) + (ex & 0xFFFFu);

        #pragma unroll
        for (int r = 0; r < 16; ++r) {
            const unsigned int g = gt0 + gtb[r];
            const unsigned int e = eq0 + eqb[r];
            const int i = (t << 4) | r;
            const unsigned long long kk =
                ((unsigned long long)u[r] << 32) | (unsigned int)(4095 - i);
            if (u[r] > Tu) {
                cld[g + (e < need ? e : need)] = kk;
            } else if (u[r] == Tu && e < need) {
                cld[g + e] = kk;
            }
        }
        __syncthreads();

        #pragma unroll
        for (int r = 0; r < 8; ++r) key[r] = cld[(t << 3) | r];
    }

    sort2048_emit(key, cld, out_idx + (size_t)qrow * TOPK, t);
}

extern "C" void kernel_launch(void* const* d_in, const int* in_sizes, int n_in,
                              void* d_out, int out_size, void* d_ws, size_t ws_size,
                              hipStream_t stream) {
    const float* q = (const float*)d_in[0];
    const float* k = (const float*)d_in[1];
    const float* w = (const float*)d_in[2];

    float* out        = (float*)d_out;
    float* out_topk   = out;
    float* out_scores = out + (size_t)SQ * TOPK;

    short8* qs = (ws_size >= QS_BYTES) ? (short8*)d_ws : (short8*)out_topk;

    split_q_kernel<<<SQ * NH * 16 / 256, 256, 0, stream>>>(q, qs);

    scores_kernel<<<dim3(SK / 128, SQ / 64), 512, 0, stream>>>(qs, k, w, out_scores);

    topk_merged_kernel<<<SQ, 256, 0, stream>>>(out_scores, out_topk);
}